// Round 14
// baseline (5172.046 us; speedup 1.0000x reference)
//
#include <hip/hip_runtime.h>
#include <hip/hip_bf16.h>
#include <math.h>

#define Bn 8
#define Tn 898
#define Dn 1024
#define Hn 16
#define DHn 64
#define Ln 12
#define FFn 4096
#define Vn 1024
#define BT (Bn*Tn)   /* 7184 */

typedef short bf16x8 __attribute__((ext_vector_type(8)));
typedef float f32x4 __attribute__((ext_vector_type(4)));

__device__ __forceinline__ ushort f2bf(float f) {
    union { float f; unsigned u; } c; c.f = f;
    unsigned r = c.u + 0x7fffu + ((c.u >> 16) & 1u);
    return (ushort)(r >> 16);
}

__device__ __forceinline__ void glds16(const void* g, void* l) {
    __builtin_amdgcn_global_load_lds(
        (const __attribute__((address_space(1))) unsigned int*)g,
        (__attribute__((address_space(3))) unsigned int*)l, 16, 0, 0);
}

#define BARRIER() __builtin_amdgcn_s_barrier()
#define SETPRIO(p) __builtin_amdgcn_s_setprio(p)
#define VMCNT0() asm volatile("s_waitcnt vmcnt(0)" ::: "memory")
#define VMCNT6() asm volatile("s_waitcnt vmcnt(6)" ::: "memory")

// ---------------- weight transpose + cast: f32 [K][N] -> bf16 [N][K] ----------------
__global__ __launch_bounds__(256) void transpose_cast_kernel(
    const float* __restrict__ in, ushort* __restrict__ out,
    int K, int N, size_t in_ls, size_t out_ls)
{
    __shared__ ushort t[64][68];
    const float* inp = in + (size_t)blockIdx.z * in_ls;
    ushort* outp = out + (size_t)blockIdx.z * out_ls;
    int n0 = blockIdx.x * 64, k0 = blockIdx.y * 64;
    int tx = threadIdx.x & 63, ty = threadIdx.x >> 6;
    #pragma unroll
    for (int p = 0; p < 16; p++) {
        int kl = p * 4 + ty;
        t[tx][kl] = f2bf(inp[(size_t)(k0 + kl) * N + n0 + tx]);
    }
    __syncthreads();
    int tx4 = threadIdx.x & 15, ty4 = threadIdx.x >> 4;
    #pragma unroll
    for (int p = 0; p < 4; p++) {
        int nl = p * 16 + ty4;
        ushort4 v;
        v.x = t[nl][4*tx4]; v.y = t[nl][4*tx4+1]; v.z = t[nl][4*tx4+2]; v.w = t[nl][4*tx4+3];
        *(ushort4*)&outp[(size_t)(n0 + nl) * K + k0 + 4*tx4] = v;
    }
}

// ---------------- embedding + positional encoding ----------------
__global__ __launch_bounds__(256) void embed_kernel(
    const int* __restrict__ tids, const int* __restrict__ pids, const int* __restrict__ oids,
    const float* __restrict__ ttab, const float* __restrict__ ptab, const float* __restrict__ otab,
    const float* __restrict__ sep, float* __restrict__ x)
{
    int bp = blockIdx.x;
    int b = bp / Tn, pos = bp - b * Tn;
    int d0 = threadIdx.x * 4;
    float4 r;
    if (pos == 128 || pos == 385) {
        r = *(const float4*)(sep + d0);
    } else {
        int t; int id; const float* tab;
        if (pos < 128)      { t = pos;       id = tids[b*128 + t]; tab = ttab; }
        else if (pos < 385) { t = pos - 129; id = pids[b*256 + t]; tab = ptab; }
        else                { t = pos - 386; id = oids[b*512 + t]; tab = otab; }
        float4 e = *(const float4*)(tab + (size_t)id * Dn + d0);
        float pe[4];
        #pragma unroll
        for (int i = 0; i < 4; i++) {
            int d = d0 + i;
            int ii = d & 511;
            float omega = expf(-9.210340371976184f * (float)ii * (1.0f/512.0f));
            float ang = (float)t * omega;
            pe[i] = (d < 512) ? sinf(ang) : cosf(ang);
        }
        r.x = e.x + pe[0]; r.y = e.y + pe[1]; r.z = e.z + pe[2]; r.w = e.w + pe[3];
    }
    *(float4*)(x + (size_t)bp * Dn + d0) = r;
}

// ---------------- layernorm fp32 -> bf16, one row per WAVE ----------
__global__ __launch_bounds__(256) void ln_kernel(
    const float* __restrict__ x, const float* __restrict__ g, const float* __restrict__ bt,
    ushort* __restrict__ out)
{
    int row = blockIdx.x * 4 + (threadIdx.x >> 6);
    int lane = threadIdx.x & 63;
    const float4* xr = (const float4*)(x + (size_t)row * Dn);
    float4 v[4];
    float s = 0.f;
    #pragma unroll
    for (int i = 0; i < 4; i++) {
        v[i] = xr[lane + 64 * i];
        s += v[i].x + v[i].y + v[i].z + v[i].w;
    }
    #pragma unroll
    for (int o = 32; o; o >>= 1) s += __shfl_xor(s, o);
    float mu = s * (1.0f / Dn);
    float s2 = 0.f;
    #pragma unroll
    for (int i = 0; i < 4; i++) {
        v[i].x -= mu; v[i].y -= mu; v[i].z -= mu; v[i].w -= mu;
        s2 += v[i].x*v[i].x + v[i].y*v[i].y + v[i].z*v[i].z + v[i].w*v[i].w;
    }
    #pragma unroll
    for (int o = 32; o; o >>= 1) s2 += __shfl_xor(s2, o);
    float rstd = rsqrtf(s2 * (1.0f / Dn) + 1e-5f);
    ushort4* orow = (ushort4*)(out + (size_t)row * Dn);
    #pragma unroll
    for (int i = 0; i < 4; i++) {
        float4 gg = ((const float4*)g)[lane + 64 * i];
        float4 bb = ((const float4*)bt)[lane + 64 * i];
        ushort4 o4;
        o4.x = f2bf(v[i].x * rstd * gg.x + bb.x);
        o4.y = f2bf(v[i].y * rstd * gg.y + bb.y);
        o4.z = f2bf(v[i].z * rstd * gg.z + bb.z);
        o4.w = f2bf(v[i].w * rstd * gg.w + bb.w);
        orow[lane + 64 * i] = o4;
    }
}

// ======== helper: XCD-chunk + M-stripe rasterization ========
__device__ __forceinline__ void raster(int nb, int bid, int nx, int S, int nmt,
                                       int& mt, int& ntt)
{
    int qq = nb >> 3, rr8 = nb & 7;
    int xcd = bid & 7, idx = bid >> 3;
    int wg = (xcd < rr8 ? xcd * (qq + 1) : rr8 * (qq + 1) + (xcd - rr8) * qq) + idx;
    int fullb = nmt / S, per = S * nx;
    if (wg < fullb * per) {
        int band = wg / per, r2 = wg - band * per;
        ntt = r2 / S; mt = band * S + (r2 - ntt * S);
    } else {
        int r2 = wg - fullb * per, bh = nmt - fullb * S;
        ntt = r2 / bh; mt = fullb * S + (r2 - ntt * bh);
    }
}

// ---------------- R10 GEMM core: 2-phase dbuf, BMxBN, 4 waves, BK=32 -------------------
// MODE 0: bf16 store; MODE 1: f32 = resid + AB + bias; MODE 2: bf16 gelu(AB + bias)
template<int BM, int BN, int MODE>
__global__ __launch_bounds__(256, 4) void gemmk(
    const ushort* __restrict__ A, const ushort* __restrict__ Bw,
    const float* __restrict__ bias, const float* __restrict__ resid,
    void* __restrict__ Cout, int M, int N, int K, int Kld, int nx, int S)
{
    constexpr int MI = BM / 32, NI = BN / 32;
    constexpr int UA = BM / 64, UB = BN / 64;
    __shared__ ushort sA[2][BM * 32];
    __shared__ ushort sB[2][BN * 32];

    int tid = threadIdx.x, lane = tid & 63, wv = tid >> 6;
    int wm = wv >> 1, wn = wv & 1;
    int l16 = lane & 15, lhi = lane >> 4;

    int mt, ntt;
    raster(gridDim.x, blockIdx.x, nx, S, (M + BM - 1) / BM, mt, ntt);
    int m0 = mt * BM, n0 = ntt * BN;

    f32x4 acc[MI][NI];
    #pragma unroll
    for (int i = 0; i < MI; i++)
        #pragma unroll
        for (int j = 0; j < NI; j++) acc[i][j] = (f32x4){0.f, 0.f, 0.f, 0.f};

    const size_t K2 = (size_t)Kld * 2;
    int srow = lane >> 2;
    int schk = ((lane & 3) ^ ((lane >> 3) & 3)) * 16;
    const char* Ap[UA];
    const char* Bp[UB];
    #pragma unroll
    for (int i = 0; i < UA; i++)
        Ap[i] = (const char*)A + (size_t)(m0 + (wv + 4 * i) * 16 + srow) * K2 + schk;
    #pragma unroll
    for (int i = 0; i < UB; i++)
        Bp[i] = (const char*)Bw + (size_t)(n0 + (wv + 4 * i) * 16 + srow) * K2 + schk;

    auto stage = [&](int buf) {
        #pragma unroll
        for (int i = 0; i < UA; i++) {
            glds16(Ap[i], (char*)sA[buf] + (wv + 4 * i) * 1024);
            Ap[i] += 64;
        }
        #pragma unroll
        for (int i = 0; i < UB; i++) {
            glds16(Bp[i], (char*)sB[buf] + (wv + 4 * i) * 1024);
            Bp[i] += 64;
        }
    };

    const int sc = (lhi ^ ((l16 >> 1) & 3)) * 8;
    auto compute = [&](int buf) {
        bf16x8 af[MI], bf[NI];
        #pragma unroll
        for (int mi = 0; mi < MI; mi++)
            af[mi] = *(const bf16x8*)&sA[buf][(wm * (16 * MI) + mi * 16 + l16) * 32 + sc];
        #pragma unroll
        for (int ni = 0; ni < NI; ni++)
            bf[ni] = *(const bf16x8*)&sB[buf][(wn * (16 * NI) + ni * 16 + l16) * 32 + sc];
        #pragma unroll
        for (int mi = 0; mi < MI; mi++)
            #pragma unroll
            for (int ni = 0; ni < NI; ni++)
                acc[mi][ni] = __builtin_amdgcn_mfma_f32_16x16x32_bf16(af[mi], bf[ni], acc[mi][ni], 0, 0, 0);
    };

    int ntile = K >> 5;
    stage(0);
    VMCNT0();
    BARRIER();
    int cur = 0;
    for (int t = 0; t < ntile; ++t) {
        if (t + 1 < ntile) stage(cur ^ 1);   // issue next-tile loads FIRST
        compute(cur);
        VMCNT0();
        BARRIER();
        cur ^= 1;
    }

    #pragma unroll
    for (int mi = 0; mi < MI; mi++) {
        int rl = wm * (16 * MI) + mi * 16 + lhi * 4;
        #pragma unroll
        for (int ni = 0; ni < NI; ni++) {
            int gcol = n0 + wn * (16 * NI) + ni * 16 + l16;
            float bs = (MODE == 1 || MODE == 2) ? bias[gcol] : 0.0f;
            #pragma unroll
            for (int j = 0; j < 4; j++) {
                int grow = m0 + rl + j;
                if (grow >= M) continue;
                float v = acc[mi][ni][j] + bs;
                if (MODE == 1) {
                    float rv = resid[(size_t)grow * N + gcol];
                    ((float*)Cout)[(size_t)grow * N + gcol] = rv + v;
                } else if (MODE == 2) {
                    float u = v * (1.5957691216f + 0.0713548163f * v * v);
                    float g = v / (1.0f + __expf(-u));
                    ((ushort*)Cout)[(size_t)grow * N + gcol] = f2bf(g);
                } else {
                    ((ushort*)Cout)[(size_t)grow * N + gcol] = f2bf(v);
                }
            }
        }
    }
}

// ---------------- faithful m201-style 8-phase 256x256 BK=64 GEMM (T2+T3+T4+T5) ------------
// 8 waves (2M x 4N), per-wave 128x64 output. LDS 2 buf x {A 256x64, B 256x64} = 128 KB,
// organized as 4 half-tiles (A0,A1,B0,B1) of 128 rows x 128 B. Per K-tile 4 phases:
//   P1 {read A(mh0)+B(nh0) | bar | 16 MFMA | bar}, P2 {read B(nh1) | ...},
//   P3 {read A(mh1); stage B0(t+2) | ...}, P4 {stage B1,A0,A1(t+2); 16 MFMA; vmcnt(6); bar}.
// Stage issued only AFTER the post-barrier of the phase that last read that region.
// vmcnt(6) = 3 half-tiles (2 loads each) in flight; vmcnt(0) only in the tail pair.
template<int MODE>
__global__ __launch_bounds__(512, 2) void gemm8p(
    const ushort* __restrict__ A, const ushort* __restrict__ Bw,
    const float* __restrict__ bias, void* __restrict__ Cout,
    int M, int N, int K, int nx, int S)
{
    __shared__ ushort lds[2][2][2][128 * 64];   // [buf][op A0/B1][half][row*64+col] = 128 KB

    int tid = threadIdx.x, lane = tid & 63, wv = tid >> 6;
    int wm = wv >> 2, wn = wv & 3;
    int l16 = lane & 15, lhi = lane >> 4;

    int mt, ntt;
    raster(gridDim.x, blockIdx.x, nx, S, (M + 255) >> 8, mt, ntt);
    int m0 = mt * 256, n0 = ntt * 256;

    f32x4 acc[8][4];
    #pragma unroll
    for (int i = 0; i < 8; i++)
        #pragma unroll
        for (int j = 0; j < 4; j++) acc[i][j] = (f32x4){0.f, 0.f, 0.f, 0.f};

    // staging: half-tile = 128 rows x 128 B = 16 units of (8 rows x 128 B); wave wv owns
    // units wv*2, wv*2+1. lane -> row lane>>3, source chunk (lane&7)^(row&7) (pre-swizzled).
    const size_t K2 = (size_t)K * 2;
    int srow = lane >> 3;
    int schk = ((lane & 7) ^ srow) * 16;
    const char* Sp[4][2];     // [hid: 0=A0,1=A1,2=B0,3=B1][unit j]
    #pragma unroll
    for (int j = 0; j < 2; j++) {
        int r = (wv * 2 + j) * 8 + srow;
        Sp[0][j] = (const char*)A  + (size_t)(m0 + r)       * K2 + schk;
        Sp[1][j] = (const char*)A  + (size_t)(m0 + 128 + r) * K2 + schk;
        Sp[2][j] = (const char*)Bw + (size_t)(n0 + r)       * K2 + schk;
        Sp[3][j] = (const char*)Bw + (size_t)(n0 + 128 + r) * K2 + schk;
    }

    auto stageH = [&](int hid, int buf) {
        #pragma unroll
        for (int j = 0; j < 2; j++) {
            glds16(Sp[hid][j], (char*)&lds[buf][hid >> 1][hid & 1][0] + (wv * 2 + j) * 1024);
            Sp[hid][j] += 128;                 // advance one K-tile (64 elems * 2B)
        }
    };

    bf16x8 afr[4][2], bfr0[2][2], bfr1[2][2];
    const int bhalf = wn >> 1, brow0 = (wn & 1) * 64;

    auto LDA = [&](int buf, int mh) {
        #pragma unroll
        for (int mi = 0; mi < 4; mi++) {
            int row = mh * 64 + mi * 16 + l16;
            #pragma unroll
            for (int ks = 0; ks < 2; ks++) {
                int sw = (((ks << 2) | lhi) ^ (l16 & 7)) * 8;
                afr[mi][ks] = *(const bf16x8*)&lds[buf][0][wm][row * 64 + sw];
            }
        }
    };
    auto LDB = [&](bf16x8 (&b)[2][2], int buf, int nh) {
        #pragma unroll
        for (int ni = 0; ni < 2; ni++) {
            int row = brow0 + nh * 32 + ni * 16 + l16;
            #pragma unroll
            for (int ks = 0; ks < 2; ks++) {
                int sw = (((ks << 2) | lhi) ^ (l16 & 7)) * 8;
                b[ni][ks] = *(const bf16x8*)&lds[buf][1][bhalf][row * 64 + sw];
            }
        }
    };
    auto MM = [&](int mh, int nh, bf16x8 (&b)[2][2]) {
        #pragma unroll
        for (int ks = 0; ks < 2; ks++)
            #pragma unroll
            for (int mi = 0; mi < 4; mi++)
                #pragma unroll
                for (int ni = 0; ni < 2; ni++)
                    acc[mh*4+mi][nh*2+ni] = __builtin_amdgcn_mfma_f32_16x16x32_bf16(
                        afr[mi][ks], b[ni][ks], acc[mh*4+mi][nh*2+ni], 0, 0, 0);
    };

    int ntile = K >> 6;   // BK=64
    // prologue: tile0 -> buf0 (any order); tile1 -> buf1 in per-iter issue order B0,B1,A0,A1.
    stageH(0,0); stageH(1,0); stageH(2,0); stageH(3,0);
    stageH(2,1); stageH(3,1); stageH(0,1); stageH(1,1);
    VMCNT6();            // tile0 fully landed + tile1's B0; 3 half-tiles of tile1 in flight
    BARRIER();

    for (int t = 0; t < ntile; t += 2) {
        const bool st2 = (t + 2) < ntile;
        const bool st3 = (t + 3) < ntile;
        // ======== K-tile t (buf0), staging t+2 -> buf0 ========
        LDA(0, 0); LDB(bfr0, 0, 0);                           // P1: 12 ds_reads
        BARRIER();
        SETPRIO(1); MM(0, 0, bfr0); SETPRIO(0);
        BARRIER();
        LDB(bfr1, 0, 1);                                      // P2: 4 ds_reads
        BARRIER();
        SETPRIO(1); MM(0, 1, bfr1); SETPRIO(0);
        BARRIER();
        LDA(0, 1);                                            // P3: 8 ds_reads; B free -> stage B0
        if (st2) stageH(2, 0);
        BARRIER();
        SETPRIO(1); MM(1, 1, bfr1); SETPRIO(0);
        BARRIER();
        if (st2) { stageH(3, 0); stageH(0, 0); stageH(1, 0); }// P4: A free -> stage B1,A0,A1
        SETPRIO(1); MM(1, 0, bfr0); SETPRIO(0);
        if (st2) { VMCNT6(); } else { VMCNT0(); }
        BARRIER();
        // ======== K-tile t+1 (buf1), staging t+3 -> buf1 ========
        LDA(1, 0); LDB(bfr0, 1, 0);
        BARRIER();
        SETPRIO(1); MM(0, 0, bfr0); SETPRIO(0);
        BARRIER();
        LDB(bfr1, 1, 1);
        BARRIER();
        SETPRIO(1); MM(0, 1, bfr1); SETPRIO(0);
        BARRIER();
        LDA(1, 1);
        if (st3) stageH(2, 1);
        BARRIER();
        SETPRIO(1); MM(1, 1, bfr1); SETPRIO(0);
        BARRIER();
        if (st3) { stageH(3, 1); stageH(0, 1); stageH(1, 1); }
        SETPRIO(1); MM(1, 0, bfr0); SETPRIO(0);
        if (st3) { VMCNT6(); } else { VMCNT0(); }
        BARRIER();
    }

    // epilogue: acc[mf][nf], row = wm*128 + (mf>>2)*64 + (mf&3)*16, col = wn*64 + (nf>>1)*32 + (nf&1)*16
    #pragma unroll
    for (int mf = 0; mf < 8; mf++) {
        int rb = m0 + wm * 128 + (mf >> 2) * 64 + (mf & 3) * 16 + lhi * 4;
        #pragma unroll
        for (int nf = 0; nf < 4; nf++) {
            int gcol = n0 + wn * 64 + (nf >> 1) * 32 + (nf & 1) * 16 + l16;
            float bs = (MODE == 2) ? bias[gcol] : 0.0f;
            #pragma unroll
            for (int j = 0; j < 4; j++) {
                int grow = rb + j;
                if (grow >= M) continue;
                float v = acc[mf][nf][j] + bs;
                if (MODE == 2) {
                    float u = v * (1.5957691216f + 0.0713548163f * v * v);
                    float g = v / (1.0f + __expf(-u));
                    ((ushort*)Cout)[(size_t)grow * N + gcol] = f2bf(g);
                } else {
                    ((ushort*)Cout)[(size_t)grow * N + gcol] = f2bf(v);
                }
            }
        }
    }
}

// ---------------- flash attention (causal), bf16 in/out ----------------
__global__ __launch_bounds__(256) void attn_kernel(
    const ushort* __restrict__ qkv, ushort* __restrict__ out)
{
    __shared__ ushort Ksm[64 * 72];
    __shared__ ushort Vsm[64 * 72];
    __shared__ ushort Psm[4][16 * 72];
    int qt = blockIdx.x, b = blockIdx.y, h = blockIdx.z;
    int tid = threadIdx.x, lane = tid & 63, wave = tid >> 6;
    int l16 = lane & 15, lhi = lane >> 4;

    int qrow = qt*64 + wave*16 + l16;
    bf16x8 qf0 = {}, qf1 = {};
    if (qrow < Tn) {
        const ushort* qp = qkv + (size_t)(b*Tn + qrow) * 3072 + h*64 + lhi*8;
        qf0 = *(const bf16x8*)qp;
        qf1 = *(const bf16x8*)(qp + 32);
    }

    f32x4 o[4];
    #pragma unroll
    for (int i = 0; i < 4; i++) o[i] = (f32x4){0.f,0.f,0.f,0.f};
    float mrun[4] = {-1e30f,-1e30f,-1e30f,-1e30f};
    float sume[4] = {0.f,0.f,0.f,0.f};

    int kr = tid >> 2, cc = (tid & 3) * 16;
    const ushort* kvbase = qkv + (size_t)(b*Tn) * 3072 + h*64 + cc;
    int qg = qt*64 + wave*16 + lhi*4;

    for (int jt = 0; jt <= qt; jt++) {
        int kvr = jt*64 + kr;
        uint4 k0 = make_uint4(0,0,0,0), k1 = k0, v0 = k0, v1 = k0;
        if (kvr < Tn) {
            const ushort* p = kvbase + (size_t)kvr * 3072;
            k0 = *(const uint4*)(p + 1024);
            k1 = *(const uint4*)(p + 1024 + 8);
            v0 = *(const uint4*)(p + 2048);
            v1 = *(const uint4*)(p + 2048 + 8);
        }
        __syncthreads();
        *(uint4*)&Ksm[kr * 72 + cc] = k0;
        *(uint4*)&Ksm[kr * 72 + cc + 8] = k1;
        {
            ushort vv[16];
            *(uint4*)&vv[0] = v0; *(uint4*)&vv[8] = v1;
            #pragma unroll
            for (int i = 0; i < 16; i++) Vsm[(cc + i) * 72 + kr] = vv[i];
        }
        __syncthreads();

        f32x4 s[4];
        #pragma unroll
        for (int ni = 0; ni < 4; ni++) {
            s[ni] = (f32x4){0.f,0.f,0.f,0.f};
            bf16x8 kf0 = *(const bf16x8*)&Ksm[(ni*16 + l16) * 72 + lhi*8];
            bf16x8 kf1 = *(const bf16x8*)&Ksm[(ni*16 + l16) * 72 + lhi*8 + 32];
            s[ni] = __builtin_amdgcn_mfma_f32_16x16x32_bf16(qf0, kf0, s[ni], 0, 0, 0);
            s[ni] = __builtin_amdgcn_mfma_f32_16x16x32_bf16(qf1, kf1, s[ni], 0, 0, 0);
        }

        float pv[4][4];
        #pragma unroll
        for (int j = 0; j < 4; j++) {
            int qgj = qg + j;
            float mx = -1e30f;
            #pragma unroll
            for (int ni = 0; ni < 4; ni++) {
                int kvg = jt*64 + ni*16 + l16;
                float e = (kvg <= qgj && kvg < Tn) ? s[ni][j] * 0.125f : -1e30f;
                pv[ni][j] = e;
                mx = fmaxf(mx, e);
            }
            #pragma unroll
            for (int m = 1; m < 16; m <<= 1) mx = fmaxf(mx, __shfl_xor(mx, m));
            float mnew = fmaxf(mrun[j], mx);
            float fac = expf(mrun[j] - mnew);
            mrun[j] = mnew;
            float rs = 0.f;
            #pragma unroll
            for (int ni = 0; ni < 4; ni++) { pv[ni][j] = expf(pv[ni][j] - mnew); rs += pv[ni][j]; }
            #pragma unroll
            for (int m = 1; m < 16; m <<= 1) rs += __shfl_xor(rs, m);
            sume[j] = sume[j] * fac + rs;
            #pragma unroll
            for (int di = 0; di < 4; di++) o[di][j] *= fac;
        }

        #pragma unroll
        for (int j = 0; j < 4; j++)
            #pragma unroll
            for (int ni = 0; ni < 4; ni++)
                Psm[wave][(lhi*4 + j) * 72 + ni*16 + l16] = f2bf(pv[ni][j]);
        __syncthreads();

        bf16x8 pf0 = *(const bf16x8*)&Psm[wave][l16 * 72 + lhi*8];
        bf16x8 pf1 = *(const bf16x8*)&Psm[wave][l16 * 72 + lhi*8 + 32];
        #pragma unroll
        for (int di = 0; di < 4; di++) {
            bf16x8 vf0 = *(const bf16x8*)&Vsm[(di*16 + l16) * 72 + lhi*8];
            bf16x8 vf1 = *(const bf16x8*)&Vsm[(di*16 + l16) * 72 + lhi*8 + 32];
            o[di] = __builtin_amdgcn_mfma_f32_16x16x32_bf16(pf0, vf0, o[di], 0, 0, 0);
            o[di] = __builtin_amdgcn_mfma_f32_16x16x32_bf16(pf1, vf1, o[di], 0, 0, 0);
        }
    }

    #pragma unroll
    for (int j = 0; j < 4; j++) {
        int qgj = qg + j;
        if (qgj >= Tn) continue;
        float inv = 1.0f / sume[j];
        #pragma unroll
        for (int di = 0; di < 4; di++)
            out[(size_t)(b*Tn + qgj) * Dn + h*64 + di*16 + l16] = f2bf(o[di][j] * inv);
    }
}

// ---------------- final fc on last position ----------------
__global__ __launch_bounds__(256) void fc_kernel(
    const float* __restrict__ x, const float* __restrict__ w,
    const float* __restrict__ bias, float* __restrict__ out)
{
    __shared__ float xs[Dn];
    int b = blockIdx.y;
    int v = blockIdx.x * 256 + threadIdx.x;
    float4 t = ((const float4*)(x + (size_t)(b*Tn + Tn - 1) * Dn))[threadIdx.x];
    ((float4*)xs)[threadIdx.x] = t;
    __syncthreads();
    float acc = bias[v];
    for (int d = 0; d < Dn; d++)
        acc = fmaf(xs[d], w[(size_t)d * Vn + v], acc);
    out[(size_t)b * Vn + v] = acc;
}

extern "C" void kernel_launch(void* const* d_in, const int* in_sizes, int n_in,
                              void* d_out, int out_size, void* d_ws, size_t ws_size,
                              hipStream_t stream)
{
    const int*   text_ids  = (const int*)d_in[0];
    const int*   prompt_ids= (const int*)d_in[1];
    const int*   output_ids= (const int*)d_in[2];
    const float* text_tab  = (const float*)d_in[3];
    const float* prompt_tab= (const float*)d_in[4];
    const float* output_tab= (const float*)d_in[5];
    const float* sep       = (const float*)d_in[6];
    const float* ln1_g     = (const float*)d_in[7];
    const float* ln1_b     = (const float*)d_in[8];
    const float* qkv_w     = (const float*)d_in[9];
    const float* out_w     = (const float*)d_in[10];
    const float* out_b     = (const float*)d_in[11];
    const float* ln2_g     = (const float*)d_in[12];
    const float* ln2_b     = (const float*)d_in[13];
    const float* ff1_w     = (const float*)d_in[14];
    const float* ff1_b     = (const float*)d_in[15];
    const float* ff2_w     = (const float*)d_in[16];
    const float* ff2_b     = (const float*)d_in[17];
    const float* fc_w      = (const float*)d_in[18];
    const float* fc_b      = (const float*)d_in[19];

    char* ws = (char*)d_ws;
    float*  x    = (float*)(ws);                    // [7184][1024] f32 = 29,425,664
    ushort* h    = (ushort*)(ws + 29425664);        // [7424][1024] bf16 = 15,204,352
    ushort* qkv  = (ushort*)(ws + 44630016);        // [7424][3072] bf16 = 45,613,056
    ushort* attn = (ushort*)(ws + 90243072);        // [7424][1024] bf16 = 15,204,352
    ushort* ff1o = (ushort*)(ws + 105447424);       // [7424][4096] bf16 = 60,817,408
    ushort* wT   = (ushort*)(ws + 166264832);       // weights bf16 [N][K]

    const size_t L_STRIDE = 12582912;        // ushorts per layer block
    const size_t OFF_QKV = 0, OFF_OUT = 3145728, OFF_FF1 = 4194304, OFF_FF2 = 8388608;
    const size_t upfront_need = 166264832ULL + 2ULL * L_STRIDE * Ln;
    const bool upfront = ws_size >= upfront_need;

    if (upfront) {
        transpose_cast_kernel<<<dim3(48,16,Ln), 256, 0, stream>>>(qkv_w, wT + OFF_QKV, Dn, 3*Dn, (size_t)Dn*3*Dn, L_STRIDE);
        transpose_cast_kernel<<<dim3(16,16,Ln), 256, 0, stream>>>(out_w, wT + OFF_OUT, Dn, Dn,   (size_t)Dn*Dn,   L_STRIDE);
        transpose_cast_kernel<<<dim3(64,16,Ln), 256, 0, stream>>>(ff1_w, wT + OFF_FF1, Dn, FFn,  (size_t)Dn*FFn,  L_STRIDE);
        transpose_cast_kernel<<<dim3(16,64,Ln), 256, 0, stream>>>(ff2_w, wT + OFF_FF2, FFn, Dn,  (size_t)FFn*Dn,  L_STRIDE);
    }

    embed_kernel<<<BT, 256, 0, stream>>>(text_ids, prompt_ids, output_ids,
                                         text_tab, prompt_tab, output_tab, sep, x);

    for (int l = 0; l < Ln; l++) {
        ushort* wb = upfront ? (wT + (size_t)l * L_STRIDE) : wT;
        if (!upfront) {
            transpose_cast_kernel<<<dim3(48,16,1), 256, 0, stream>>>(qkv_w + (size_t)l*Dn*3*Dn, wb + OFF_QKV, Dn, 3*Dn, 0, 0);
            transpose_cast_kernel<<<dim3(16,16,1), 256, 0, stream>>>(out_w + (size_t)l*Dn*Dn,   wb + OFF_OUT, Dn, Dn,   0, 0);
            transpose_cast_kernel<<<dim3(64,16,1), 256, 0, stream>>>(ff1_w + (size_t)l*Dn*FFn,  wb + OFF_FF1, Dn, FFn,  0, 0);
            transpose_cast_kernel<<<dim3(16,64,1), 256, 0, stream>>>(ff2_w + (size_t)l*FFn*Dn,  wb + OFF_FF2, FFn, Dn,  0, 0);
        }
        ln_kernel<<<BT/4, 256, 0, stream>>>(x, ln1_g + l*Dn, ln1_b + l*Dn, h);
        gemm8p<0><<<29*12, 512, 0, stream>>>(
            h, wb + OFF_QKV, nullptr, qkv, BT, 3*Dn, Dn, 12, 4);
        attn_kernel<<<dim3(15, Bn, Hn), 256, 0, stream>>>(qkv, attn);
        gemmk<64,128,1><<<113*8, 256, 0, stream>>>(
            attn, wb + OFF_OUT, out_b + l*Dn, x, x, BT, Dn, Dn, Dn, 8, 4);
        ln_kernel<<<BT/4, 256, 0, stream>>>(x, ln2_g + l*Dn, ln2_b + l*Dn, h);
        gemm8p<2><<<29*16, 512, 0, stream>>>(
            h, wb + OFF_FF1, ff1_b + l*FFn, ff1o, BT, FFn, Dn, 16, 4);
        gemmk<64,128,1><<<113*8, 256, 0, stream>>>(
            ff1o, wb + OFF_FF2, ff2_b + l*Dn, x, x, BT, Dn, FFn, FFn, 8, 4);
    }

    fc_kernel<<<dim3(Vn/256, Bn), 256, 0, stream>>>(x, fc_w, fc_b, (float*)d_out);
}

// Round 15
// 4933.046 us; speedup vs baseline: 1.0484x; 1.0484x over previous
//
#include <hip/hip_runtime.h>
#include <hip/hip_bf16.h>
#include <math.h>

#define Bn 8
#define Tn 898
#define Dn 1024
#define Hn 16
#define DHn 64
#define Ln 12
#define FFn 4096
#define Vn 1024
#define BT (Bn*Tn)   /* 7184 */

typedef short bf16x8 __attribute__((ext_vector_type(8)));
typedef float f32x4 __attribute__((ext_vector_type(4)));

__device__ __forceinline__ ushort f2bf(float f) {
    union { float f; unsigned u; } c; c.f = f;
    unsigned r = c.u + 0x7fffu + ((c.u >> 16) & 1u);
    return (ushort)(r >> 16);
}

__device__ __forceinline__ void glds16(const void* g, void* l) {
    __builtin_amdgcn_global_load_lds(
        (const __attribute__((address_space(1))) unsigned int*)g,
        (__attribute__((address_space(3))) unsigned int*)l, 16, 0, 0);
}

#define BARRIER() __builtin_amdgcn_s_barrier()
#define VMCNT0() asm volatile("s_waitcnt vmcnt(0)" ::: "memory")

// ---------------- weight transpose + cast: f32 [K][N] -> bf16 [N][K] ----------------
__global__ __launch_bounds__(256) void transpose_cast_kernel(
    const float* __restrict__ in, ushort* __restrict__ out,
    int K, int N, size_t in_ls, size_t out_ls)
{
    __shared__ ushort t[64][68];
    const float* inp = in + (size_t)blockIdx.z * in_ls;
    ushort* outp = out + (size_t)blockIdx.z * out_ls;
    int n0 = blockIdx.x * 64, k0 = blockIdx.y * 64;
    int tx = threadIdx.x & 63, ty = threadIdx.x >> 6;
    #pragma unroll
    for (int p = 0; p < 16; p++) {
        int kl = p * 4 + ty;
        t[tx][kl] = f2bf(inp[(size_t)(k0 + kl) * N + n0 + tx]);
    }
    __syncthreads();
    int tx4 = threadIdx.x & 15, ty4 = threadIdx.x >> 4;
    #pragma unroll
    for (int p = 0; p < 4; p++) {
        int nl = p * 16 + ty4;
        ushort4 v;
        v.x = t[nl][4*tx4]; v.y = t[nl][4*tx4+1]; v.z = t[nl][4*tx4+2]; v.w = t[nl][4*tx4+3];
        *(ushort4*)&outp[(size_t)(n0 + nl) * K + k0 + 4*tx4] = v;
    }
}

// ---------------- embedding + positional encoding ----------------
__global__ __launch_bounds__(256) void embed_kernel(
    const int* __restrict__ tids, const int* __restrict__ pids, const int* __restrict__ oids,
    const float* __restrict__ ttab, const float* __restrict__ ptab, const float* __restrict__ otab,
    const float* __restrict__ sep, float* __restrict__ x)
{
    int bp = blockIdx.x;
    int b = bp / Tn, pos = bp - b * Tn;
    int d0 = threadIdx.x * 4;
    float4 r;
    if (pos == 128 || pos == 385) {
        r = *(const float4*)(sep + d0);
    } else {
        int t; int id; const float* tab;
        if (pos < 128)      { t = pos;       id = tids[b*128 + t]; tab = ttab; }
        else if (pos < 385) { t = pos - 129; id = pids[b*256 + t]; tab = ptab; }
        else                { t = pos - 386; id = oids[b*512 + t]; tab = otab; }
        float4 e = *(const float4*)(tab + (size_t)id * Dn + d0);
        float pe[4];
        #pragma unroll
        for (int i = 0; i < 4; i++) {
            int d = d0 + i;
            int ii = d & 511;
            float omega = expf(-9.210340371976184f * (float)ii * (1.0f/512.0f));
            float ang = (float)t * omega;
            pe[i] = (d < 512) ? sinf(ang) : cosf(ang);
        }
        r.x = e.x + pe[0]; r.y = e.y + pe[1]; r.z = e.z + pe[2]; r.w = e.w + pe[3];
    }
    *(float4*)(x + (size_t)bp * Dn + d0) = r;
}

// ---------------- layernorm fp32 -> bf16, one row per WAVE, 8 rows/block ----------
__global__ __launch_bounds__(512) void ln_kernel(
    const float* __restrict__ x, const float* __restrict__ g, const float* __restrict__ bt,
    ushort* __restrict__ out)
{
    int row = blockIdx.x * 8 + (threadIdx.x >> 6);
    int lane = threadIdx.x & 63;
    const float4* xr = (const float4*)(x + (size_t)row * Dn);
    float4 v[4];
    float s = 0.f;
    #pragma unroll
    for (int i = 0; i < 4; i++) {
        v[i] = xr[lane + 64 * i];
        s += v[i].x + v[i].y + v[i].z + v[i].w;
    }
    #pragma unroll
    for (int o = 32; o; o >>= 1) s += __shfl_xor(s, o);
    float mu = s * (1.0f / Dn);
    float s2 = 0.f;
    #pragma unroll
    for (int i = 0; i < 4; i++) {
        v[i].x -= mu; v[i].y -= mu; v[i].z -= mu; v[i].w -= mu;
        s2 += v[i].x*v[i].x + v[i].y*v[i].y + v[i].z*v[i].z + v[i].w*v[i].w;
    }
    #pragma unroll
    for (int o = 32; o; o >>= 1) s2 += __shfl_xor(s2, o);
    float rstd = rsqrtf(s2 * (1.0f / Dn) + 1e-5f);
    ushort4* orow = (ushort4*)(out + (size_t)row * Dn);
    #pragma unroll
    for (int i = 0; i < 4; i++) {
        float4 gg = ((const float4*)g)[lane + 64 * i];
        float4 bb = ((const float4*)bt)[lane + 64 * i];
        ushort4 o4;
        o4.x = f2bf(v[i].x * rstd * gg.x + bb.x);
        o4.y = f2bf(v[i].y * rstd * gg.y + bb.y);
        o4.z = f2bf(v[i].z * rstd * gg.z + bb.z);
        o4.w = f2bf(v[i].w * rstd * gg.w + bb.w);
        orow[lane + 64 * i] = o4;
    }
}

// ======== helper: XCD-chunk + M-stripe rasterization ========
__device__ __forceinline__ void raster(int nb, int bid, int nx, int S, int nmt,
                                       int& mt, int& ntt)
{
    int qq = nb >> 3, rr8 = nb & 7;
    int xcd = bid & 7, idx = bid >> 3;
    int wg = (xcd < rr8 ? xcd * (qq + 1) : rr8 * (qq + 1) + (xcd - rr8) * qq) + idx;
    int fullb = nmt / S, per = S * nx;
    if (wg < fullb * per) {
        int band = wg / per, r2 = wg - band * per;
        ntt = r2 / S; mt = band * S + (r2 - ntt * S);
    } else {
        int r2 = wg - fullb * per, bh = nmt - fullb * S;
        ntt = r2 / bh; mt = fullb * S + (r2 - ntt * bh);
    }
}

// ---------------- R10 GEMM core: 2-phase dbuf, BMxBN, 4 waves, BK=32 -------------------
// MODE 0: bf16 store; MODE 1: f32 = resid + AB + bias; MODE 2: bf16 gelu(AB + bias)
template<int BM, int BN, int MODE>
__global__ __launch_bounds__(256, 4) void gemmk(
    const ushort* __restrict__ A, const ushort* __restrict__ Bw,
    const float* __restrict__ bias, const float* __restrict__ resid,
    void* __restrict__ Cout, int M, int N, int K, int nx, int S)
{
    constexpr int MI = BM / 32, NI = BN / 32;
    constexpr int UA = BM / 64, UB = BN / 64;
    __shared__ ushort sA[2][BM * 32];
    __shared__ ushort sB[2][BN * 32];

    int tid = threadIdx.x, lane = tid & 63, wv = tid >> 6;
    int wm = wv >> 1, wn = wv & 1;
    int l16 = lane & 15, lhi = lane >> 4;

    int mt, ntt;
    raster(gridDim.x, blockIdx.x, nx, S, (M + BM - 1) / BM, mt, ntt);
    int m0 = mt * BM, n0 = ntt * BN;

    f32x4 acc[MI][NI];
    #pragma unroll
    for (int i = 0; i < MI; i++)
        #pragma unroll
        for (int j = 0; j < NI; j++) acc[i][j] = (f32x4){0.f, 0.f, 0.f, 0.f};

    const size_t K2 = (size_t)K * 2;
    int srow = lane >> 2;
    int schk = ((lane & 3) ^ ((lane >> 3) & 3)) * 16;
    const char* Ap[UA];
    const char* Bp[UB];
    #pragma unroll
    for (int i = 0; i < UA; i++)
        Ap[i] = (const char*)A + (size_t)(m0 + (wv + 4 * i) * 16 + srow) * K2 + schk;
    #pragma unroll
    for (int i = 0; i < UB; i++)
        Bp[i] = (const char*)Bw + (size_t)(n0 + (wv + 4 * i) * 16 + srow) * K2 + schk;

    auto stage = [&](int buf) {
        #pragma unroll
        for (int i = 0; i < UA; i++) {
            glds16(Ap[i], (char*)sA[buf] + (wv + 4 * i) * 1024);
            Ap[i] += 64;
        }
        #pragma unroll
        for (int i = 0; i < UB; i++) {
            glds16(Bp[i], (char*)sB[buf] + (wv + 4 * i) * 1024);
            Bp[i] += 64;
        }
    };

    const int sc = (lhi ^ ((l16 >> 1) & 3)) * 8;
    auto compute = [&](int buf) {
        bf16x8 af[MI], bf[NI];
        #pragma unroll
        for (int mi = 0; mi < MI; mi++)
            af[mi] = *(const bf16x8*)&sA[buf][(wm * (16 * MI) + mi * 16 + l16) * 32 + sc];
        #pragma unroll
        for (int ni = 0; ni < NI; ni++)
            bf[ni] = *(const bf16x8*)&sB[buf][(wn * (16 * NI) + ni * 16 + l16) * 32 + sc];
        #pragma unroll
        for (int mi = 0; mi < MI; mi++)
            #pragma unroll
            for (int ni = 0; ni < NI; ni++)
                acc[mi][ni] = __builtin_amdgcn_mfma_f32_16x16x32_bf16(af[mi], bf[ni], acc[mi][ni], 0, 0, 0);
    };

    int ntile = K >> 5;
    stage(0);
    VMCNT0();
    BARRIER();
    int cur = 0;
    for (int t = 0; t < ntile; ++t) {
        if (t + 1 < ntile) stage(cur ^ 1);   // issue next-tile loads FIRST (latency hides under MFMA)
        compute(cur);
        VMCNT0();
        BARRIER();
        cur ^= 1;
    }

    #pragma unroll
    for (int mi = 0; mi < MI; mi++) {
        int rl = wm * (16 * MI) + mi * 16 + lhi * 4;
        #pragma unroll
        for (int ni = 0; ni < NI; ni++) {
            int gcol = n0 + wn * (16 * NI) + ni * 16 + l16;
            float bs = (MODE == 0) ? 0.0f : bias[gcol];
            #pragma unroll
            for (int j = 0; j < 4; j++) {
                int grow = m0 + rl + j;
                if (grow >= M) continue;
                float v = acc[mi][ni][j] + bs;
                if (MODE == 1) {
                    float rv = resid[(size_t)grow * N + gcol];
                    ((float*)Cout)[(size_t)grow * N + gcol] = rv + v;
                } else if (MODE == 2) {
                    // gelu(v) ~= v * sigmoid(1.5957691216 v + 0.0713548163 v^3)
                    float u = v * (1.5957691216f + 0.0713548163f * v * v);
                    float g = v / (1.0f + __expf(-u));
                    ((ushort*)Cout)[(size_t)grow * N + gcol] = f2bf(g);
                } else {
                    ((ushort*)Cout)[(size_t)grow * N + gcol] = f2bf(v);
                }
            }
        }
    }
}

// ---------------- flash attention (causal), bf16 in/out ----------------
__global__ __launch_bounds__(256) void attn_kernel(
    const ushort* __restrict__ qkv, ushort* __restrict__ out)
{
    __shared__ ushort Ksm[64 * 72];
    __shared__ ushort Vsm[64 * 72];
    __shared__ ushort Psm[4][16 * 72];
    int qt = blockIdx.x, b = blockIdx.y, h = blockIdx.z;
    int tid = threadIdx.x, lane = tid & 63, wave = tid >> 6;
    int l16 = lane & 15, lhi = lane >> 4;

    int qrow = qt*64 + wave*16 + l16;
    bf16x8 qf0 = {}, qf1 = {};
    if (qrow < Tn) {
        const ushort* qp = qkv + (size_t)(b*Tn + qrow) * 3072 + h*64 + lhi*8;
        qf0 = *(const bf16x8*)qp;
        qf1 = *(const bf16x8*)(qp + 32);
    }

    f32x4 o[4];
    #pragma unroll
    for (int i = 0; i < 4; i++) o[i] = (f32x4){0.f,0.f,0.f,0.f};
    float mrun[4] = {-1e30f,-1e30f,-1e30f,-1e30f};
    float sume[4] = {0.f,0.f,0.f,0.f};

    int kr = tid >> 2, cc = (tid & 3) * 16;
    const ushort* kvbase = qkv + (size_t)(b*Tn) * 3072 + h*64 + cc;
    int qg = qt*64 + wave*16 + lhi*4;

    for (int jt = 0; jt <= qt; jt++) {
        int kvr = jt*64 + kr;
        uint4 k0 = make_uint4(0,0,0,0), k1 = k0, v0 = k0, v1 = k0;
        if (kvr < Tn) {
            const ushort* p = kvbase + (size_t)kvr * 3072;
            k0 = *(const uint4*)(p + 1024);
            k1 = *(const uint4*)(p + 1024 + 8);
            v0 = *(const uint4*)(p + 2048);
            v1 = *(const uint4*)(p + 2048 + 8);
        }
        __syncthreads();
        *(uint4*)&Ksm[kr * 72 + cc] = k0;
        *(uint4*)&Ksm[kr * 72 + cc + 8] = k1;
        {
            ushort vv[16];
            *(uint4*)&vv[0] = v0; *(uint4*)&vv[8] = v1;
            #pragma unroll
            for (int i = 0; i < 16; i++) Vsm[(cc + i) * 72 + kr] = vv[i];
        }
        __syncthreads();

        f32x4 s[4];
        #pragma unroll
        for (int ni = 0; ni < 4; ni++) {
            s[ni] = (f32x4){0.f,0.f,0.f,0.f};
            bf16x8 kf0 = *(const bf16x8*)&Ksm[(ni*16 + l16) * 72 + lhi*8];
            bf16x8 kf1 = *(const bf16x8*)&Ksm[(ni*16 + l16) * 72 + lhi*8 + 32];
            s[ni] = __builtin_amdgcn_mfma_f32_16x16x32_bf16(qf0, kf0, s[ni], 0, 0, 0);
            s[ni] = __builtin_amdgcn_mfma_f32_16x16x32_bf16(qf1, kf1, s[ni], 0, 0, 0);
        }

        float pv[4][4];
        #pragma unroll
        for (int j = 0; j < 4; j++) {
            int qgj = qg + j;
            float mx = -1e30f;
            #pragma unroll
            for (int ni = 0; ni < 4; ni++) {
                int kvg = jt*64 + ni*16 + l16;
                float e = (kvg <= qgj && kvg < Tn) ? s[ni][j] * 0.125f : -1e30f;
                pv[ni][j] = e;
                mx = fmaxf(mx, e);
            }
            #pragma unroll
            for (int m = 1; m < 16; m <<= 1) mx = fmaxf(mx, __shfl_xor(mx, m));
            float mnew = fmaxf(mrun[j], mx);
            float fac = expf(mrun[j] - mnew);
            mrun[j] = mnew;
            float rs = 0.f;
            #pragma unroll
            for (int ni = 0; ni < 4; ni++) { pv[ni][j] = expf(pv[ni][j] - mnew); rs += pv[ni][j]; }
            #pragma unroll
            for (int m = 1; m < 16; m <<= 1) rs += __shfl_xor(rs, m);
            sume[j] = sume[j] * fac + rs;
            #pragma unroll
            for (int di = 0; di < 4; di++) o[di][j] *= fac;
        }

        #pragma unroll
        for (int j = 0; j < 4; j++)
            #pragma unroll
            for (int ni = 0; ni < 4; ni++)
                Psm[wave][(lhi*4 + j) * 72 + ni*16 + l16] = f2bf(pv[ni][j]);
        __syncthreads();

        bf16x8 pf0 = *(const bf16x8*)&Psm[wave][l16 * 72 + lhi*8];
        bf16x8 pf1 = *(const bf16x8*)&Psm[wave][l16 * 72 + lhi*8 + 32];
        #pragma unroll
        for (int di = 0; di < 4; di++) {
            bf16x8 vf0 = *(const bf16x8*)&Vsm[(di*16 + l16) * 72 + lhi*8];
            bf16x8 vf1 = *(const bf16x8*)&Vsm[(di*16 + l16) * 72 + lhi*8 + 32];
            o[di] = __builtin_amdgcn_mfma_f32_16x16x32_bf16(pf0, vf0, o[di], 0, 0, 0);
            o[di] = __builtin_amdgcn_mfma_f32_16x16x32_bf16(pf1, vf1, o[di], 0, 0, 0);
        }
    }

    #pragma unroll
    for (int j = 0; j < 4; j++) {
        int qgj = qg + j;
        if (qgj >= Tn) continue;
        float inv = 1.0f / sume[j];
        #pragma unroll
        for (int di = 0; di < 4; di++)
            out[(size_t)(b*Tn + qgj) * Dn + h*64 + di*16 + l16] = f2bf(o[di][j] * inv);
    }
}

// ---------------- final fc on last position ----------------
__global__ __launch_bounds__(256) void fc_kernel(
    const float* __restrict__ x, const float* __restrict__ w,
    const float* __restrict__ bias, float* __restrict__ out)
{
    __shared__ float xs[Dn];
    int b = blockIdx.y;
    int v = blockIdx.x * 256 + threadIdx.x;
    float4 t = ((const float4*)(x + (size_t)(b*Tn + Tn - 1) * Dn))[threadIdx.x];
    ((float4*)xs)[threadIdx.x] = t;
    __syncthreads();
    float acc = bias[v];
    for (int d = 0; d < Dn; d++)
        acc = fmaf(xs[d], w[(size_t)d * Vn + v], acc);
    out[(size_t)b * Vn + v] = acc;
}

extern "C" void kernel_launch(void* const* d_in, const int* in_sizes, int n_in,
                              void* d_out, int out_size, void* d_ws, size_t ws_size,
                              hipStream_t stream)
{
    const int*   text_ids  = (const int*)d_in[0];
    const int*   prompt_ids= (const int*)d_in[1];
    const int*   output_ids= (const int*)d_in[2];
    const float* text_tab  = (const float*)d_in[3];
    const float* prompt_tab= (const float*)d_in[4];
    const float* output_tab= (const float*)d_in[5];
    const float* sep       = (const float*)d_in[6];
    const float* ln1_g     = (const float*)d_in[7];
    const float* ln1_b     = (const float*)d_in[8];
    const float* qkv_w     = (const float*)d_in[9];
    const float* out_w     = (const float*)d_in[10];
    const float* out_b     = (const float*)d_in[11];
    const float* ln2_g     = (const float*)d_in[12];
    const float* ln2_b     = (const float*)d_in[13];
    const float* ff1_w     = (const float*)d_in[14];
    const float* ff1_b     = (const float*)d_in[15];
    const float* ff2_w     = (const float*)d_in[16];
    const float* ff2_b     = (const float*)d_in[17];
    const float* fc_w      = (const float*)d_in[18];
    const float* fc_b      = (const float*)d_in[19];

    char* ws = (char*)d_ws;
    float*  x    = (float*)(ws);                    // [7184][1024] f32 = 29,425,664
    ushort* h    = (ushort*)(ws + 29425664);        // [7424][1024] bf16 = 15,204,352
    ushort* qkv  = (ushort*)(ws + 44630016);        // [7424][3072] bf16 = 45,613,056
    ushort* attn = (ushort*)(ws + 90243072);        // [7424][1024] bf16 = 15,204,352
    ushort* ff1o = (ushort*)(ws + 105447424);       // [7424][4096] bf16 = 60,817,408
    ushort* wT   = (ushort*)(ws + 166264832);       // weights bf16 [N][K]

    const size_t L_STRIDE = 12582912;        // ushorts per layer block
    const size_t OFF_QKV = 0, OFF_OUT = 3145728, OFF_FF1 = 4194304, OFF_FF2 = 8388608;
    const size_t upfront_need = 166264832ULL + 2ULL * L_STRIDE * Ln;
    const bool upfront = ws_size >= upfront_need;

    if (upfront) {
        transpose_cast_kernel<<<dim3(48,16,Ln), 256, 0, stream>>>(qkv_w, wT + OFF_QKV, Dn, 3*Dn, (size_t)Dn*3*Dn, L_STRIDE);
        transpose_cast_kernel<<<dim3(16,16,Ln), 256, 0, stream>>>(out_w, wT + OFF_OUT, Dn, Dn,   (size_t)Dn*Dn,   L_STRIDE);
        transpose_cast_kernel<<<dim3(64,16,Ln), 256, 0, stream>>>(ff1_w, wT + OFF_FF1, Dn, FFn,  (size_t)Dn*FFn,  L_STRIDE);
        transpose_cast_kernel<<<dim3(16,64,Ln), 256, 0, stream>>>(ff2_w, wT + OFF_FF2, FFn, Dn,  (size_t)FFn*Dn,  L_STRIDE);
    }

    embed_kernel<<<BT, 256, 0, stream>>>(text_ids, prompt_ids, output_ids,
                                         text_tab, prompt_tab, output_tab, sep, x);

    for (int l = 0; l < Ln; l++) {
        ushort* wb = upfront ? (wT + (size_t)l * L_STRIDE) : wT;
        if (!upfront) {
            transpose_cast_kernel<<<dim3(48,16,1), 256, 0, stream>>>(qkv_w + (size_t)l*Dn*3*Dn, wb + OFF_QKV, Dn, 3*Dn, 0, 0);
            transpose_cast_kernel<<<dim3(16,16,1), 256, 0, stream>>>(out_w + (size_t)l*Dn*Dn,   wb + OFF_OUT, Dn, Dn,   0, 0);
            transpose_cast_kernel<<<dim3(64,16,1), 256, 0, stream>>>(ff1_w + (size_t)l*Dn*FFn,  wb + OFF_FF1, Dn, FFn,  0, 0);
            transpose_cast_kernel<<<dim3(16,64,1), 256, 0, stream>>>(ff2_w + (size_t)l*FFn*Dn,  wb + OFF_FF2, FFn, Dn,  0, 0);
        }
        ln_kernel<<<BT/8, 512, 0, stream>>>(x, ln1_g + l*Dn, ln1_b + l*Dn, h);
        gemmk<128,128,0><<<57*24, 256, 0, stream>>>(
            h, wb + OFF_QKV, nullptr, nullptr, qkv, BT, 3*Dn, Dn, 24, 8);
        attn_kernel<<<dim3(15, Bn, Hn), 256, 0, stream>>>(qkv, attn);
        gemmk<64,128,1><<<113*8, 256, 0, stream>>>(
            attn, wb + OFF_OUT, out_b + l*Dn, x, x, BT, Dn, Dn, 8, 4);
        ln_kernel<<<BT/8, 512, 0, stream>>>(x, ln2_g + l*Dn, ln2_b + l*Dn, h);
        gemmk<128,128,2><<<57*32, 256, 0, stream>>>(
            h, wb + OFF_FF1, ff1_b + l*FFn, nullptr, ff1o, BT, FFn, Dn, 32, 8);
        gemmk<64,128,1><<<113*8, 256, 0, stream>>>(
            ff1o, wb + OFF_FF2, ff2_b + l*Dn, x, x, BT, Dn, FFn, 8, 4);
    }

    fc_kernel<<<dim3(Vn/256, Bn), 256, 0, stream>>>(x, fc_w, fc_b, (float*)d_out);
}